// Round 5
// baseline (307.529 us; speedup 1.0000x reference)
//
#include <hip/hip_runtime.h>

#define NROW 16384
#define DDIM 128

typedef _Float16 f16x8 __attribute__((ext_vector_type(8)));
typedef float f32x4 __attribute__((ext_vector_type(4)));
typedef float f32x16 __attribute__((ext_vector_type(16)));

__device__ __forceinline__ unsigned short f2h(float x) {
  union { _Float16 f; unsigned short u; } cvt;
  cvt.f = (_Float16)x;
  return cvt.u;
}

// Raw barrier without vmcnt(0) drain (prefetch stays in flight).
__device__ __forceinline__ void block_sync() {
  asm volatile("s_waitcnt lgkmcnt(0)" ::: "memory");
  __builtin_amdgcn_s_barrier();
  asm volatile("" ::: "memory");
}

// ---------------- prep: hq[k>>3][d][k&7] = fp16(h[k][d]) ----------------
// 8-k-tiled layout so fused-kernel staging is coalesced and ds_reads are
// contiguous per lane (no swizzle needed anywhere).
__global__ __launch_bounds__(256) void prep_hq(const float* __restrict__ h,
                                               unsigned short* __restrict__ hq) {
  __shared__ unsigned short tile[DDIM][65];  // [d][k_local], padded
  const int t = threadIdx.x;
  const int k0 = blockIdx.x * 64;
#pragma unroll
  for (int rep = 0; rep < 8; ++rep) {
    int idx = rep * 256 + t;          // 2048 float4s of a 64k x 128d tile
    int r = idx >> 5, c4 = idx & 31;
    const float4 v = *(const float4*)(h + (size_t)(k0 + r) * DDIM + c4 * 4);
    int c = c4 * 4;
    tile[c + 0][r] = f2h(v.x);
    tile[c + 1][r] = f2h(v.y);
    tile[c + 2][r] = f2h(v.z);
    tile[c + 3][r] = f2h(v.w);
  }
  __syncthreads();
#pragma unroll
  for (int rep = 0; rep < 4; ++rep) {
    int idx = rep * 256 + t;          // 0..1023: chunk c = idx>>7, d = idx&127
    int c = idx >> 7, d = idx & 127;
    int ko = c * 8;
    uint4 o;
    o.x = (unsigned)tile[d][ko + 0] | ((unsigned)tile[d][ko + 1] << 16);
    o.y = (unsigned)tile[d][ko + 2] | ((unsigned)tile[d][ko + 3] << 16);
    o.z = (unsigned)tile[d][ko + 4] | ((unsigned)tile[d][ko + 5] << 16);
    o.w = (unsigned)tile[d][ko + 6] | ((unsigned)tile[d][ko + 7] << 16);
    *(uint4*)(hq + (size_t)k0 * DDIM + idx * 8) = o;
  }
}

// ---------------- fused: out = rownorm(exp(adj)) @ h ----------------
// BM=32 rows/block, grid 512 (2 blocks/CU, 8 waves/CU). 32x32x16 f16 MFMA.
// Wave w owns k-chunk kk=w (16 k per 64-k tile) x all 128 d (4 col frags).
// A: adj global->reg directly in A-frag layout, exp once per element.
// B: hq staged coalesced -> linear LDS (dbuf 2x16KB), conflict-free reads.
// One raw barrier per iter. Cross-wave partial-k reduction once at the end.
__global__ __launch_bounds__(256, 2) void fused(const float* __restrict__ adj,
                                                const unsigned short* __restrict__ hq,
                                                float* __restrict__ out) {
  __shared__ __align__(16) char bsm[32768];
  __shared__ float rsw[4][32];
  const int t = threadIdx.x;
  const int l = t & 63, w = t >> 6;      // wave = k-chunk owner
  const int row = l & 31, hh = l >> 5;
  const size_t m0 = (size_t)blockIdx.x * 32;

  // A: lane covers adj[m0+row][it*64 + w*16 + hh*8 .. +7]
  const float* abase = adj + (m0 + row) * (size_t)NROW + w * 16 + hh * 8;
  // B staging: thread t stages 4x16B per iter, fully coalesced
  const unsigned short* qsrc = hq + t * 8;
  // B fragment read base: chunk (w*2+hh), col cg*32+row
  const int rdoff = (w * 2 + hh) * 2048 + row * 16;

  f32x16 acc[4];
#pragma unroll
  for (int cg = 0; cg < 4; ++cg)
#pragma unroll
    for (int e = 0; e < 16; ++e) acc[cg][e] = 0.f;
  float rs = 0.f;

  // prologue: prefetch tile 0
  float4 pa0 = *(const float4*)(abase);
  float4 pa1 = *(const float4*)(abase + 4);
  uint4 pq0 = *(const uint4*)(qsrc);
  uint4 pq1 = *(const uint4*)(qsrc + 2048);
  uint4 pq2 = *(const uint4*)(qsrc + 4096);
  uint4 pq3 = *(const uint4*)(qsrc + 6144);

  for (int it = 0; it < NROW / 64; ++it) {
    const int cur = it & 1;
    char* wbuf = bsm + cur * 16384;

    // 1. write staged B to LDS (linear, conflict-free)
    *(uint4*)(wbuf + t * 16)         = pq0;
    *(uint4*)(wbuf + t * 16 + 4096)  = pq1;
    *(uint4*)(wbuf + t * 16 + 8192)  = pq2;
    *(uint4*)(wbuf + t * 16 + 12288) = pq3;

    // 2. consume A: exp + pack + rowsum (each adj element exactly once)
    const float e0 = __expf(pa0.x), e1 = __expf(pa0.y);
    const float e2 = __expf(pa0.z), e3 = __expf(pa0.w);
    const float e4 = __expf(pa1.x), e5 = __expf(pa1.y);
    const float e6 = __expf(pa1.z), e7 = __expf(pa1.w);
    rs += ((e0 + e1) + (e2 + e3)) + ((e4 + e5) + (e6 + e7));
    f16x8 af;
    af[0] = (_Float16)e0; af[1] = (_Float16)e1;
    af[2] = (_Float16)e2; af[3] = (_Float16)e3;
    af[4] = (_Float16)e4; af[5] = (_Float16)e5;
    af[6] = (_Float16)e6; af[7] = (_Float16)e7;

    // 3. prefetch tile it+1 (stays in flight across the raw barrier)
    const int nk = (it + 1) & 255;     // wraps on last iter (harmless)
    pa0 = *(const float4*)(abase + nk * 64);
    pa1 = *(const float4*)(abase + nk * 64 + 4);
    const unsigned short* q = qsrc + nk * 8192;
    pq0 = *(const uint4*)(q);
    pq1 = *(const uint4*)(q + 2048);
    pq2 = *(const uint4*)(q + 4096);
    pq3 = *(const uint4*)(q + 6144);

    // 4. barrier (ds_writes visible; global prefetch NOT drained)
    block_sync();

    // 5. B fragments + MFMA (4 independent acc chains)
    const char* rbuf = bsm + cur * 16384 + rdoff;
#pragma unroll
    for (int cg = 0; cg < 4; ++cg) {
      const f16x8 bf = *(const f16x8*)(rbuf + cg * 512);
      acc[cg] = __builtin_amdgcn_mfma_f32_32x32x16_f16(af, bf, acc[cg], 0, 0, 0);
    }
  }

  // ---- rowsum: combine hh halves, publish per-wave partials ----
  rs += __shfl_xor(rs, 32);
  if (l < 32) rsw[w][l] = rs;
  __syncthreads();

  // ---- cross-wave reduction of partial-k accumulators ----
  // Round cg: all waves dump acc[cg]; wave w==cg sums 4 partials, divides by
  // total rowsum, writes out cols cg*32..+31.
  for (int cg = 0; cg < 4; ++cg) {
#pragma unroll
    for (int q4 = 0; q4 < 4; ++q4) {
      f32x4 v;
      v[0] = acc[cg][q4 * 4 + 0]; v[1] = acc[cg][q4 * 4 + 1];
      v[2] = acc[cg][q4 * 4 + 2]; v[3] = acc[cg][q4 * 4 + 3];
      *(f32x4*)(bsm + w * 4096 + l * 64 + q4 * 16) = v;
    }
    __syncthreads();
    if (w == cg) {
      float sum[16];
#pragma unroll
      for (int q4 = 0; q4 < 4; ++q4) {
        f32x4 s = *(const f32x4*)(bsm + 0 * 4096 + l * 64 + q4 * 16);
#pragma unroll
        for (int w2 = 1; w2 < 4; ++w2) {
          const f32x4 v = *(const f32x4*)(bsm + w2 * 4096 + l * 64 + q4 * 16);
          s[0] += v[0]; s[1] += v[1]; s[2] += v[2]; s[3] += v[3];
        }
        sum[q4 * 4 + 0] = s[0]; sum[q4 * 4 + 1] = s[1];
        sum[q4 * 4 + 2] = s[2]; sum[q4 * 4 + 3] = s[3];
      }
#pragma unroll
      for (int r = 0; r < 16; ++r) {
        const int orow = (r & 3) + 8 * (r >> 2) + 4 * hh;
        const float tot = ((rsw[0][orow] + rsw[1][orow]) +
                           (rsw[2][orow] + rsw[3][orow]));
        out[(m0 + orow) * (size_t)DDIM + cg * 32 + row] = sum[r] / tot;
      }
    }
    __syncthreads();
  }
}

extern "C" void kernel_launch(void* const* d_in, const int* in_sizes, int n_in,
                              void* d_out, int out_size, void* d_ws, size_t ws_size,
                              hipStream_t stream) {
  (void)in_sizes; (void)n_in; (void)out_size; (void)ws_size;
  const float* h   = (const float*)d_in[0];
  const float* adj = (const float*)d_in[1];
  float* out = (float*)d_out;
  unsigned short* hq = (unsigned short*)d_ws;  // 16384*128 fp16 = 4 MB, tiled

  prep_hq<<<dim3(NROW / 64), dim3(256), 0, stream>>>(h, hq);
  fused<<<dim3(NROW / 32), dim3(256), 0, stream>>>(adj, hq, out);
}